// Round 4
// baseline (164.760 us; speedup 1.0000x reference)
//
#include <hip/hip_runtime.h>
#include <stdint.h>

typedef __attribute__((ext_vector_type(4))) float floatx4;
typedef __attribute__((ext_vector_type(2))) long longx2;

#define CDIM   256
#define KCODES 1024

__device__ __forceinline__ void gload16(const void* g, void* l) {
    __builtin_amdgcn_global_load_lds((const __attribute__((address_space(1))) void*)g,
                                     (__attribute__((address_space(3))) void*)l, 16, 0, 0);
}
__device__ __forceinline__ unsigned pk4_fp8(float a, float b, float c, float d) {
    int u = __builtin_amdgcn_cvt_pk_fp8_f32(a, b, 0, false);
    u = __builtin_amdgcn_cvt_pk_fp8_f32(c, d, u, true);
    return (unsigned)u;
}

// ---------------- emb -> emb8 [kt][k][64B] fp8(256*e), K-permuted; e_sqs = 4096*e_sq
// byte(kt,k,q,ks,j0) = kt*65536 + k*64 + (q ^ ((k>>1)&3))*16 + ks*8 + j0
//   (kt = c>>6, ks = (c&63)>>5, q = (c&31)>>3, j0 = c&7)
// The q-XOR spreads the fb ds_read_b128 across all 32 banks (conflict-free);
// reader applies the same XOR (rule: swizzle both sides, LDS dest stays linear).
__global__ void emb_prep(const float* __restrict__ emb, unsigned char* __restrict__ emb8,
                         float* __restrict__ e_sqs) {
    int k = blockIdx.x, l = threadIdx.x;            // 64 lanes
    float4 v = ((const float4*)(emb + (size_t)k * CDIM))[l];
    float s = v.x * v.x + v.y * v.y + v.z * v.z + v.w * v.w;
    int c = l * 4;
    int kt = c >> 6, cl = c & 63;
    int ks = cl >> 5, q = (cl & 31) >> 3, j0 = cl & 7;
    unsigned pk = pk4_fp8(v.x * 256.f, v.y * 256.f, v.z * 256.f, v.w * 256.f);
    *(unsigned*)(emb8 + ((size_t)kt << 16) + (size_t)k * 64 +
                 (q ^ ((k >> 1) & 3)) * 16 + ks * 8 + j0) = pk;
#pragma unroll
    for (int off = 32; off >= 1; off >>= 1) s += __shfl_down(s, off, 64);
    if (l == 0) e_sqs[k] = 4096.f * s;
}

// ---------------- fused: transpose+fp8 convert, fp8 MFMA argmin (B LDS-staged,
//                  prefetch-pipelined, A-frags hoisted, acc ping-pong), gather, loss
__global__ __launch_bounds__(256, 4)
void vq_fused(const float* __restrict__ z, const float* __restrict__ emb,
              const unsigned char* __restrict__ emb8, const float* __restrict__ e_sqs,
              float* __restrict__ out, float* __restrict__ loss)
{
    __shared__ __align__(16) char smem[34304];
    // overlays:
    //   phase 0 : As  = smem[0..16384)  [64 pos][256B], z2p = smem[16384..17408)
    //   K-loop  : Bs dbuf = smem[0..16384) / smem[16384..32768)  [kt4][lc64][64B]
    //   output  : smG = smem[0..32768)  [32 rows][1KB], chunk-swizzled
    unsigned char* As = (unsigned char*)smem;
    float*  z2p    = (float*)(smem + 16384);             // [4][64]
    float*  z2     = (float*)(smem + 32768);             // [64]
    unsigned* red  = (unsigned*)(smem + 33024);          // [64][4]
    unsigned* sidx = (unsigned*)(smem + 34048);          // [64]

    const int tid = threadIdx.x, wave = tid >> 6, lane = tid & 63;
    const int q = lane >> 4, r = lane & 15;
    const int m0 = blockIdx.x << 6;
    const int b = m0 >> 10, s0 = m0 & 1023;

    // ---- phase 0: load z, z_sq, convert 16*z -> fp8, K-permute+swizzle into As ----
    {
        const int p = tid & 63, cg = tid >> 6;
        const float* zb = z + ((size_t)(b * 256 + cg * 64)) * 1024 + s0 + p;
        float ps = 0.f;
#pragma unroll
        for (int qq = 0; qq < 4; ++qq)
#pragma unroll
            for (int ks = 0; ks < 2; ++ks) {
                float v[8];
#pragma unroll
                for (int j = 0; j < 8; ++j) {
                    v[j] = zb[(size_t)(ks * 32 + qq * 8 + j) * 1024];
                    ps = fmaf(v[j], v[j], ps);
                }
                uint2 w;
                w.x = pk4_fp8(16.f * v[0], 16.f * v[1], 16.f * v[2], 16.f * v[3]);
                w.y = pk4_fp8(16.f * v[4], 16.f * v[5], 16.f * v[6], 16.f * v[7]);
                const int pgl = cg * 4 + qq;
                const int pgs = (pgl & 8) | ((pgl & 7) ^ (p & 7));
                *(uint2*)(As + p * 256 + pgs * 16 + ks * 8) = w;
            }
        z2p[cg * 64 + p] = ps;
    }
    __syncthreads();
    if (tid < 64)
        z2[tid] = (z2p[tid] + z2p[64 + tid]) + (z2p[128 + tid] + z2p[192 + tid]);

    // ---- hoist A fragments: depend only on (kt, mt) -> 16 ds_read_b128, once ----
    longx2 faA[4][4];
#pragma unroll
    for (int kt = 0; kt < 4; ++kt)
#pragma unroll
        for (int mt = 0; mt < 4; ++mt) {
            const int p = mt * 16 + r;
            const int pgl = kt * 4 + q;
            const int pgs = (pgl & 8) | ((pgl & 7) ^ (r & 7));
            faA[kt][mt] = *(const longx2*)(As + p * 256 + pgs * 16);
        }
    __syncthreads();            // As region free -> becomes Bs buf0

    // ---- K-loop: 16 chunks of 64 codes, Bs dbuf, acc ping-pong (fold || MFMA) ----
    floatx4 accA[4] = {}, accB[4] = {};
    unsigned run[16];
#pragma unroll
    for (int j = 0; j < 16; ++j) run[j] = 0xFFFFFFFFu;

    const int cbase = wave * 16 + r;                 // code base within chunk
    const int fbq = (q ^ ((r >> 1) & 3)) * 16;       // swizzled fb chunk byte offset

    auto STAGE = [&](int t) {
        char* db = (char*)smem + ((t & 1) << 14);
        const size_t gs = (size_t)t << 12;
#pragma unroll
        for (int j = 0; j < 4; ++j)
            gload16(emb8 + (size_t)j * 65536 + gs + (size_t)tid * 16,
                    db + j * 4096 + tid * 16);
    };
    auto MSTEP = [&](int t, floatx4* acc) {
        const unsigned char* bb = (const unsigned char*)smem + ((t & 1) << 14)
                                  + cbase * 64 + fbq;
        longx2 fb[4];
#pragma unroll
        for (int kt = 0; kt < 4; ++kt)
            fb[kt] = *(const longx2*)(bb + kt * 4096);
#pragma unroll
        for (int kt = 0; kt < 4; ++kt)
#pragma unroll
            for (int mt = 0; mt < 4; ++mt) {
                acc[mt] = __builtin_amdgcn_mfma_f32_16x16x32_fp8_fp8(
                    faA[kt][mt][0], fb[kt][0], acc[mt], 0, 0, 0);
                acc[mt] = __builtin_amdgcn_mfma_f32_16x16x32_fp8_fp8(
                    faA[kt][mt][1], fb[kt][1], acc[mt], 0, 0, 0);
            }
    };
    // fold: v32 = 32*(16384 + 4096*e_sq) - 64*dot~  (== old (16384+ev-2dot)*32);
    // pack (v32)<<10 | code -- bit-identical to previous rounds.
    auto FOLD = [&](int t, floatx4* acc) {
        const float fb32 = fmaf(e_sqs[t * 64 + cbase], 32.f, 524288.f);
        const unsigned code = (unsigned)(t * 64 + cbase);
#pragma unroll
        for (int mt = 0; mt < 4; ++mt) {
#pragma unroll
            for (int reg = 0; reg < 4; ++reg) {
                float v = fmaf(-64.f, acc[mt][reg], fb32);
                unsigned pk = ((unsigned)v << 10) | code;
                run[(mt << 2) + reg] = min(run[(mt << 2) + reg], pk);
            }
            acc[mt] = (floatx4){0.f, 0.f, 0.f, 0.f};
        }
    };

    STAGE(0);                   // prologue: chunk 0 -> buf0
#pragma unroll 1
    for (int tt = 0; tt < 8; ++tt) {
        const int te = tt * 2;
        __syncthreads();        // drains stage(te)
        STAGE(te + 1);          // -> buf1, lands under compute(te)
        MSTEP(te, accA);
        if (tt) FOLD(te - 1, accB);      // overlap fold(prev odd) with MFMA issue
        __syncthreads();        // drains stage(te+1)
        if (tt < 7) STAGE(te + 2);       // -> buf0, lands under compute(te+1)
        MSTEP(te + 1, accB);
        FOLD(te, accA);                  // overlap fold(even) with MFMA issue
    }
    FOLD(15, accB);

    // ---- argmin merge across lanes/waves ----
#pragma unroll
    for (int j = 0; j < 16; ++j) {
        unsigned pk = run[j];
#pragma unroll
        for (int off = 1; off < 16; off <<= 1)
            pk = min(pk, (unsigned)__shfl_xor((int)pk, off, 64));
        if (r == 0)
            red[(((j >> 2) << 4) + (q << 2) + (j & 3)) * 4 + wave] = pk;
    }
    __syncthreads();
    if (tid < 64) {
        unsigned m = min(min(red[tid * 4 + 0], red[tid * 4 + 1]),
                         min(red[tid * 4 + 2], red[tid * 4 + 3]));
        sidx[tid] = m & 1023u;
        float val = (float)(m >> 10) * (1.f / 32.f);
        float d = z2[tid] + (val - 16384.f) * (1.f / 4096.f);
#pragma unroll
        for (int off = 32; off >= 1; off >>= 1) d += __shfl_down(d, off, 64);
        if (tid == 0) atomicAdd(loss, d * (1.25f / 16777216.f));
    }
    __syncthreads();

    // ---- gather + write z_q: 2 passes of 32 rows through smG (full 128B lines) ----
#pragma unroll 1
    for (int pass = 0; pass < 2; ++pass) {
        const int rbase = pass << 5;
#pragma unroll
        for (int i = 0; i < 8; ++i) {
            const int row = wave * 8 + i;                             // 0..31
            const unsigned code = sidx[rbase + row];
            const int src_chunk = (lane & 56) | ((lane & 7) ^ (row & 7));
            gload16(emb + (size_t)code * CDIM + src_chunk * 4,
                    (char*)smem + row * 1024 + lane * 16);
        }
        __syncthreads();
        {
            const int s = tid & 31, cg = tid >> 5;                    // 32 pos x 8 ch-groups
            float* ob = out + ((size_t)(b * 256 + cg * 32)) * 1024 + s0 + rbase + s;
#pragma unroll
            for (int c4 = 0; c4 < 8; ++c4) {
                const int lc4 = cg * 8 + c4;                          // logical 16B chunk
                const int p16 = (lc4 & 56) | ((lc4 & 7) ^ (s & 7));   // swizzled position
                float4 v = *(const float4*)((const char*)smem + s * 1024 + p16 * 16);
                ob[(size_t)(c4 * 4 + 0) * 1024] = v.x;
                ob[(size_t)(c4 * 4 + 1) * 1024] = v.y;
                ob[(size_t)(c4 * 4 + 2) * 1024] = v.z;
                ob[(size_t)(c4 * 4 + 3) * 1024] = v.w;
            }
        }
        if (pass == 0) __syncthreads();   // last pass: no trailing barrier needed
    }
}

extern "C" void kernel_launch(void* const* d_in, const int* in_sizes, int n_in,
                              void* d_out, int out_size, void* d_ws, size_t ws_size,
                              hipStream_t stream)
{
    const float* z   = (const float*)d_in[0];
    const float* emb = (const float*)d_in[1];
    float* out = (float*)d_out;

    unsigned char* emb8 = (unsigned char*)d_ws;           // 256 KB
    float* e_sqs = (float*)((char*)d_ws + 262144);        // 4 KB
    float* loss  = out + 16777216;

    hipMemsetAsync(loss, 0, sizeof(float), stream);
    emb_prep<<<KCODES, 64, 0, stream>>>(emb, emb8, e_sqs);
    vq_fused<<<1024, 256, 0, stream>>>(z, emb, emb8, e_sqs, out, loss);
}

// Round 6
// 146.726 us; speedup vs baseline: 1.1229x; 1.1229x over previous
//
#include <hip/hip_runtime.h>
#include <stdint.h>

typedef __attribute__((ext_vector_type(4))) float floatx4;
typedef __attribute__((ext_vector_type(2))) long longx2;

#define CDIM   256
#define KCODES 1024

__device__ __forceinline__ void gload16(const void* g, void* l) {
    __builtin_amdgcn_global_load_lds((const __attribute__((address_space(1))) void*)g,
                                     (__attribute__((address_space(3))) void*)l, 16, 0, 0);
}
__device__ __forceinline__ unsigned pk4_fp8(float a, float b, float c, float d) {
    int u = __builtin_amdgcn_cvt_pk_fp8_f32(a, b, 0, false);
    u = __builtin_amdgcn_cvt_pk_fp8_f32(c, d, u, true);
    return (unsigned)u;
}

// ---------------- emb -> emb8 [kt][k][64B] fp8(256*e), K-permuted; e_sqs = 4096*e_sq
// byte(kt,k,q,ks,j0) = kt*65536 + k*64 + (q ^ ((k>>1)&3))*16 + ks*8 + j0
//   (kt = c>>6, ks = (c&63)>>5, q = (c&31)>>3, j0 = c&7)
// q-XOR spreads the fb ds_read_b128 across all 32 banks; the vq_fused reader
// applies the same XOR. LDS staging dest stays linear (global_load_lds rule).
// Block 0 also zeroes the loss accumulator (replaces a separate memset launch).
__global__ void emb_prep(const float* __restrict__ emb, unsigned char* __restrict__ emb8,
                         float* __restrict__ e_sqs, float* __restrict__ loss) {
    int k = blockIdx.x, l = threadIdx.x;            // 64 lanes
    if (k == 0 && l == 0) *loss = 0.f;
    float4 v = ((const float4*)(emb + (size_t)k * CDIM))[l];
    float s = v.x * v.x + v.y * v.y + v.z * v.z + v.w * v.w;
    int c = l * 4;
    int kt = c >> 6, cl = c & 63;
    int ks = cl >> 5, q = (cl & 31) >> 3, j0 = cl & 7;
    unsigned pk = pk4_fp8(v.x * 256.f, v.y * 256.f, v.z * 256.f, v.w * 256.f);
    *(unsigned*)(emb8 + ((size_t)kt << 16) + (size_t)k * 64 +
                 (q ^ ((k >> 1) & 3)) * 16 + ks * 8 + j0) = pk;
#pragma unroll
    for (int off = 32; off >= 1; off >>= 1) s += __shfl_down(s, off, 64);
    if (l == 0) e_sqs[k] = 4096.f * s;
}

// ---------------- fused: transpose+fp8 convert, fp8 MFMA argmin (B LDS-staged,
//                  prefetch-pipelined, A-fragments hoisted to regs), gather, loss
// Structure is the round-2 (61us) kernel EXACTLY; only the fb swizzle added.
__global__ __launch_bounds__(256, 4)
void vq_fused(const float* __restrict__ z, const float* __restrict__ emb,
              const unsigned char* __restrict__ emb8, const float* __restrict__ e_sqs,
              float* __restrict__ out, float* __restrict__ loss)
{
    __shared__ __align__(16) char smem[34304];
    // overlays:
    //   phase 0 : As  = smem[0..16384)  [64 pos][256B], z2p = smem[16384..17408)
    //   K-loop  : Bs dbuf = smem[0..16384) / smem[16384..32768)  [kt4][lc64][64B]
    //   output  : smG = smem[0..32768)  [32 rows][1KB], chunk-swizzled
    unsigned char* As = (unsigned char*)smem;
    float*  z2p    = (float*)(smem + 16384);             // [4][64]
    float*  z2     = (float*)(smem + 32768);             // [64]
    unsigned* red  = (unsigned*)(smem + 33024);          // [64][4]
    unsigned* sidx = (unsigned*)(smem + 34048);          // [64]

    const int tid = threadIdx.x, wave = tid >> 6, lane = tid & 63;
    const int q = lane >> 4, r = lane & 15;
    const int m0 = blockIdx.x << 6;
    const int b = m0 >> 10, s0 = m0 & 1023;

    // ---- phase 0: load z, z_sq, convert 16*z -> fp8, K-permute+swizzle into As ----
    {
        const int p = tid & 63, cg = tid >> 6;
        const float* zb = z + ((size_t)(b * 256 + cg * 64)) * 1024 + s0 + p;
        float ps = 0.f;
#pragma unroll
        for (int qq = 0; qq < 4; ++qq)
#pragma unroll
            for (int ks = 0; ks < 2; ++ks) {
                float v[8];
#pragma unroll
                for (int j = 0; j < 8; ++j) {
                    v[j] = zb[(size_t)(ks * 32 + qq * 8 + j) * 1024];
                    ps = fmaf(v[j], v[j], ps);
                }
                uint2 w;
                w.x = pk4_fp8(16.f * v[0], 16.f * v[1], 16.f * v[2], 16.f * v[3]);
                w.y = pk4_fp8(16.f * v[4], 16.f * v[5], 16.f * v[6], 16.f * v[7]);
                const int pgl = cg * 4 + qq;
                const int pgs = (pgl & 8) | ((pgl & 7) ^ (p & 7));
                *(uint2*)(As + p * 256 + pgs * 16 + ks * 8) = w;
            }
        z2p[cg * 64 + p] = ps;
    }
    __syncthreads();
    if (tid < 64)
        z2[tid] = (z2p[tid] + z2p[64 + tid]) + (z2p[128 + tid] + z2p[192 + tid]);

    // ---- hoist A fragments: depend only on (kt, mt) -> 16 ds_read_b128, once ----
    longx2 faA[4][4];
#pragma unroll
    for (int kt = 0; kt < 4; ++kt)
#pragma unroll
        for (int mt = 0; mt < 4; ++mt) {
            const int p = mt * 16 + r;
            const int pgl = kt * 4 + q;
            const int pgs = (pgl & 8) | ((pgl & 7) ^ (r & 7));
            faA[kt][mt] = *(const longx2*)(As + p * 256 + pgs * 16);
        }
    __syncthreads();            // As region free -> becomes Bs buf0

    // ---- K-loop: 16 chunks of 64 codes, Bs double-buffered, prefetch depth 1 ----
    floatx4 acc[4] = {};
    unsigned run[16];
#pragma unroll
    for (int j = 0; j < 16; ++j) run[j] = 0xFFFFFFFFu;

    const int cbase = wave * 16 + r;                 // code base within chunk
    const int fbq = (q ^ ((r >> 1) & 3)) * 16;       // swizzled fb chunk byte offset

    // prologue: stage chunk 0 into buf0 (16KB = 4 x gload16/thread, linear dest)
#pragma unroll
    for (int j = 0; j < 4; ++j)
        gload16(emb8 + (size_t)j * 65536 + tid * 16,
                (char*)smem + j * 4096 + tid * 16);

#pragma unroll 1
    for (int t = 0; t < 16; ++t) {
        __syncthreads();        // drains stage(t)'s loads; all waves past compute(t-1)
        if (t < 15) {           // issue stage(t+1) -> lands under compute(t)
            char* db = (char*)smem + (((t + 1) & 1) << 14);
            const size_t gs = (size_t)(t + 1) * 4096;
#pragma unroll
            for (int j = 0; j < 4; ++j)
                gload16(emb8 + (size_t)j * 65536 + gs + tid * 16,
                        db + j * 4096 + tid * 16);
        }
        const unsigned char* bb = (const unsigned char*)smem + ((t & 1) << 14);
        const float ev = e_sqs[t * 64 + cbase];
#pragma unroll
        for (int kt = 0; kt < 4; ++kt) {
            const longx2 fb = *(const longx2*)(bb + kt * 4096 + cbase * 64 + fbq);
#pragma unroll
            for (int mt = 0; mt < 4; ++mt) {
                acc[mt] = __builtin_amdgcn_mfma_f32_16x16x32_fp8_fp8(
                    faA[kt][mt][0], fb[0], acc[mt], 0, 0, 0);
                acc[mt] = __builtin_amdgcn_mfma_f32_16x16x32_fp8_fp8(
                    faA[kt][mt][1], fb[1], acc[mt], 0, 0, 0);
            }
        }
        // fold: val = 16384 + 4096*e_sq - 2*dot~ ; pack (val*32)<<10 | code
        const int code = t * 64 + cbase;
#pragma unroll
        for (int mt = 0; mt < 4; ++mt) {
#pragma unroll
            for (int reg = 0; reg < 4; ++reg) {
                float v = 16384.f + ev - 2.f * acc[mt][reg];
                unsigned pk = ((unsigned)(v * 32.f) << 10) | (unsigned)code;
                run[(mt << 2) + reg] = min(run[(mt << 2) + reg], pk);
            }
            acc[mt] = (floatx4){0.f, 0.f, 0.f, 0.f};
        }
    }

    // ---- argmin merge across lanes/waves ----
#pragma unroll
    for (int j = 0; j < 16; ++j) {
        unsigned pk = run[j];
#pragma unroll
        for (int off = 1; off < 16; off <<= 1)
            pk = min(pk, (unsigned)__shfl_xor((int)pk, off, 64));
        if (r == 0)
            red[(((j >> 2) << 4) + (q << 2) + (j & 3)) * 4 + wave] = pk;
    }
    __syncthreads();
    if (tid < 64) {
        unsigned m = min(min(red[tid * 4 + 0], red[tid * 4 + 1]),
                         min(red[tid * 4 + 2], red[tid * 4 + 3]));
        sidx[tid] = m & 1023u;
        float val = (float)(m >> 10) * (1.f / 32.f);
        float d = z2[tid] + (val - 16384.f) * (1.f / 4096.f);
#pragma unroll
        for (int off = 32; off >= 1; off >>= 1) d += __shfl_down(d, off, 64);
        if (tid == 0) atomicAdd(loss, d * (1.25f / 16777216.f));
    }
    __syncthreads();

    // ---- gather + write z_q: 2 passes of 32 rows through smG (full 128B lines) ----
#pragma unroll 1
    for (int pass = 0; pass < 2; ++pass) {
        const int rbase = pass << 5;
#pragma unroll
        for (int i = 0; i < 8; ++i) {
            const int row = wave * 8 + i;                             // 0..31
            const unsigned code = sidx[rbase + row];
            const int src_chunk = (lane & 56) | ((lane & 7) ^ (row & 7));
            gload16(emb + (size_t)code * CDIM + src_chunk * 4,
                    (char*)smem + row * 1024 + lane * 16);
        }
        __syncthreads();
        {
            const int s = tid & 31, cg = tid >> 5;                    // 32 pos x 8 ch-groups
            float* ob = out + ((size_t)(b * 256 + cg * 32)) * 1024 + s0 + rbase + s;
#pragma unroll
            for (int c4 = 0; c4 < 8; ++c4) {
                const int lc4 = cg * 8 + c4;                          // logical 16B chunk
                const int p16 = (lc4 & 56) | ((lc4 & 7) ^ (s & 7));   // swizzled position
                float4 v = *(const float4*)((const char*)smem + s * 1024 + p16 * 16);
                ob[(size_t)(c4 * 4 + 0) * 1024] = v.x;
                ob[(size_t)(c4 * 4 + 1) * 1024] = v.y;
                ob[(size_t)(c4 * 4 + 2) * 1024] = v.z;
                ob[(size_t)(c4 * 4 + 3) * 1024] = v.w;
            }
        }
        __syncthreads();
    }
}

extern "C" void kernel_launch(void* const* d_in, const int* in_sizes, int n_in,
                              void* d_out, int out_size, void* d_ws, size_t ws_size,
                              hipStream_t stream)
{
    const float* z   = (const float*)d_in[0];
    const float* emb = (const float*)d_in[1];
    float* out = (float*)d_out;

    unsigned char* emb8 = (unsigned char*)d_ws;           // 256 KB
    float* e_sqs = (float*)((char*)d_ws + 262144);        // 4 KB
    float* loss  = out + 16777216;

    emb_prep<<<KCODES, 64, 0, stream>>>(emb, emb8, e_sqs, loss);
    vq_fused<<<1024, 256, 0, stream>>>(z, emb, emb8, e_sqs, out, loss);
}

// Round 7
// 138.566 us; speedup vs baseline: 1.1890x; 1.0589x over previous
//
#include <hip/hip_runtime.h>
#include <stdint.h>

typedef __attribute__((ext_vector_type(4))) float floatx4;
typedef __attribute__((ext_vector_type(2))) long longx2;

#define CDIM   256
#define KCODES 1024

__device__ __forceinline__ void gload16(const void* g, void* l) {
    __builtin_amdgcn_global_load_lds((const __attribute__((address_space(1))) void*)g,
                                     (__attribute__((address_space(3))) void*)l, 16, 0, 0);
}
__device__ __forceinline__ unsigned pk4_fp8(float a, float b, float c, float d) {
    int u = __builtin_amdgcn_cvt_pk_fp8_f32(a, b, 0, false);
    u = __builtin_amdgcn_cvt_pk_fp8_f32(c, d, u, true);
    return (unsigned)u;
}

// ---------------- emb -> emb8 [kt][k][64B] fp8(256*e), K-permuted; e_sqs = 4096*e_sq
// byte(kt,k,q,ks,j0) = kt*65536 + k*64 + (q ^ ((k>>1)&3))*16 + ks*8 + j0
// (unchanged from round 6 — swizzle + loss-zero fold both verified)
__global__ void emb_prep(const float* __restrict__ emb, unsigned char* __restrict__ emb8,
                         float* __restrict__ e_sqs, float* __restrict__ loss) {
    int k = blockIdx.x, l = threadIdx.x;            // 64 lanes
    if (k == 0 && l == 0) *loss = 0.f;
    float4 v = ((const float4*)(emb + (size_t)k * CDIM))[l];
    float s = v.x * v.x + v.y * v.y + v.z * v.z + v.w * v.w;
    int c = l * 4;
    int kt = c >> 6, cl = c & 63;
    int ks = cl >> 5, q = (cl & 31) >> 3, j0 = cl & 7;
    unsigned pk = pk4_fp8(v.x * 256.f, v.y * 256.f, v.z * 256.f, v.w * 256.f);
    *(unsigned*)(emb8 + ((size_t)kt << 16) + (size_t)k * 64 +
                 (q ^ ((k >> 1) & 3)) * 16 + ks * 8 + j0) = pk;
#pragma unroll
    for (int off = 32; off >= 1; off >>= 1) s += __shfl_down(s, off, 64);
    if (l == 0) e_sqs[k] = 4096.f * s;
}

// ---------------- fused kernel: 512 blocks x 512 threads, 128 positions/block.
// 8 waves = 4 position-groups (wm) x 2 code-halves (wn). B staged per 64-code
// chunk (16KB dbuf, separate from As -> early prologue stage, no faA barrier).
__global__ __launch_bounds__(512, 2)
void vq_fused(const float* __restrict__ z, const float* __restrict__ emb,
              const unsigned char* __restrict__ emb8, const float* __restrict__ e_sqs,
              float* __restrict__ out, float* __restrict__ loss)
{
    __shared__ __align__(16) char smem[69632];
    // As   [0, 32768)     : [128 pos][256B] fp8, K-permuted+swizzled
    // Bs   [32768, 65536) : dbuf 2 x [4 kt][64 code][64B]
    // smG  [0, 65536)     : output overlay, 64 rows x 1KB, chunk-swizzled
    // z2p  [65536, 67584) : [4][128] f32 partial z_sq
    // red  [67584, 68608) : [128 pos][2 wn] u32
    // sidx [68608, 69120) : [128] u32
    unsigned char* As = (unsigned char*)smem;
    unsigned char* Bs = (unsigned char*)(smem + 32768);
    float*  z2p    = (float*)(smem + 65536);
    unsigned* red  = (unsigned*)(smem + 67584);
    unsigned* sidx = (unsigned*)(smem + 68608);

    const int tid = threadIdx.x, wave = tid >> 6, lane = tid & 63;
    const int q = lane >> 4, r = lane & 15;
    const int wn = wave & 1, wm = wave >> 1;
    const int m0 = blockIdx.x << 7;
    const int b = m0 >> 10, s0 = m0 & 1023;

    // ---- prologue: stage chunk 0 -> buf0 NOW; latency hides under phase 0 ----
    {
        const int half = tid >> 8, tt = tid & 255;
#pragma unroll
        for (int j = 0; j < 2; ++j) {
            const int plane = half * 2 + j;
            gload16(emb8 + (size_t)plane * 65536 + tt * 16,
                    Bs + plane * 4096 + tt * 16);
        }
    }

    // ---- phase 0: load z, z_sq, convert 16*z -> fp8, K-permute+swizzle into As ----
    {
        const int p = tid & 127, cg = tid >> 7;          // 128 pos x 4 ch-groups of 64
        const float* zb = z + ((size_t)(b * 256 + cg * 64)) * 1024 + s0 + p;
        float ps = 0.f;
#pragma unroll
        for (int qq = 0; qq < 4; ++qq)
#pragma unroll
            for (int ks = 0; ks < 2; ++ks) {
                float v[8];
#pragma unroll
                for (int j = 0; j < 8; ++j) {
                    v[j] = zb[(size_t)(ks * 32 + qq * 8 + j) * 1024];
                    ps = fmaf(v[j], v[j], ps);
                }
                uint2 w;
                w.x = pk4_fp8(16.f * v[0], 16.f * v[1], 16.f * v[2], 16.f * v[3]);
                w.y = pk4_fp8(16.f * v[4], 16.f * v[5], 16.f * v[6], 16.f * v[7]);
                const int pgl = cg * 4 + qq;
                const int pgs = (pgl & 8) | ((pgl & 7) ^ (p & 7));
                *(uint2*)(As + p * 256 + pgs * 16 + ks * 8) = w;
            }
        z2p[cg * 128 + p] = ps;
    }
    __syncthreads();

    // ---- hoist A fragments: wave's 32 positions x 4 kt -> 8 ds_read_b128, once ----
    longx2 faA[4][2];
#pragma unroll
    for (int kt = 0; kt < 4; ++kt)
#pragma unroll
        for (int mt = 0; mt < 2; ++mt) {
            const int p = wm * 32 + mt * 16 + r;
            const int pgl = kt * 4 + q;
            const int pgs = (pgl & 8) | ((pgl & 7) ^ (r & 7));
            faA[kt][mt] = *(const longx2*)(As + p * 256 + pgs * 16);
        }
    // no barrier: Bs is disjoint from As; K-loop t=0 sync drains prologue stage.

    // ---- K-loop: 16 chunks of 64 codes, Bs double-buffered, prefetch depth 1 ----
    floatx4 acc[2][2] = {};
    unsigned run[8];
#pragma unroll
    for (int j = 0; j < 8; ++j) run[j] = 0xFFFFFFFFu;

    const int lc = wn * 32 + r;                      // code base within chunk (+nt*16)
    const int fbq = (q ^ ((r >> 1) & 3)) * 16;       // swizzled fb chunk byte offset

#pragma unroll 1
    for (int t = 0; t < 16; ++t) {
        __syncthreads();        // drains stage(t); all waves past compute(t-1)
        if (t < 15) {           // issue stage(t+1) -> lands under compute(t)
            char* db = (char*)Bs + (((t + 1) & 1) << 14);
            const int half = tid >> 8, tt = tid & 255;
#pragma unroll
            for (int j = 0; j < 2; ++j) {
                const int plane = half * 2 + j;
                gload16(emb8 + (size_t)plane * 65536 + (size_t)(t + 1) * 4096 + tt * 16,
                        db + plane * 4096 + tt * 16);
            }
        }
        const unsigned char* bb = (const unsigned char*)Bs + ((t & 1) << 14);
        float ev[2];
#pragma unroll
        for (int nt = 0; nt < 2; ++nt) ev[nt] = e_sqs[t * 64 + lc + nt * 16];
        longx2 fb[4][2];
#pragma unroll
        for (int kt = 0; kt < 4; ++kt)
#pragma unroll
            for (int nt = 0; nt < 2; ++nt)
                fb[kt][nt] = *(const longx2*)(bb + kt * 4096 + (lc + nt * 16) * 64 + fbq);
#pragma unroll
        for (int kt = 0; kt < 4; ++kt)
#pragma unroll
            for (int mt = 0; mt < 2; ++mt)
#pragma unroll
                for (int nt = 0; nt < 2; ++nt) {
                    acc[mt][nt] = __builtin_amdgcn_mfma_f32_16x16x32_fp8_fp8(
                        faA[kt][mt][0], fb[kt][nt][0], acc[mt][nt], 0, 0, 0);
                    acc[mt][nt] = __builtin_amdgcn_mfma_f32_16x16x32_fp8_fp8(
                        faA[kt][mt][1], fb[kt][nt][1], acc[mt][nt], 0, 0, 0);
                }
        // fold: val = 16384 + 4096*e_sq - 2*dot~ ; pack (val*32)<<10 | code
#pragma unroll
        for (int mt = 0; mt < 2; ++mt) {
#pragma unroll
            for (int nt = 0; nt < 2; ++nt) {
                const unsigned code = (unsigned)(t * 64 + lc + nt * 16);
#pragma unroll
                for (int reg = 0; reg < 4; ++reg) {
                    float v = 16384.f + ev[nt] - 2.f * acc[mt][nt][reg];
                    unsigned pk = ((unsigned)(v * 32.f) << 10) | code;
                    run[(mt << 2) + reg] = min(run[(mt << 2) + reg], pk);
                }
                acc[mt][nt] = (floatx4){0.f, 0.f, 0.f, 0.f};
            }
        }
    }

    // ---- argmin merge: reduce over r (codes), then across code-halves via red ----
#pragma unroll
    for (int j = 0; j < 8; ++j) {
        unsigned pk = run[j];
#pragma unroll
        for (int off = 1; off < 16; off <<= 1)
            pk = min(pk, (unsigned)__shfl_xor((int)pk, off, 64));
        if (r == 0)
            red[(wm * 32 + ((j >> 2) << 4) + (q << 2) + (j & 3)) * 2 + wn] = pk;
    }
    __syncthreads();
    if (tid < 128) {
        unsigned m = min(red[tid * 2 + 0], red[tid * 2 + 1]);
        sidx[tid] = m & 1023u;
        float val = (float)(m >> 10) * (1.f / 32.f);
        float d = (z2p[tid] + z2p[128 + tid]) + (z2p[256 + tid] + z2p[384 + tid])
                + (val - 16384.f) * (1.f / 4096.f);
#pragma unroll
        for (int off = 32; off >= 1; off >>= 1) d += __shfl_down(d, off, 64);
        if (lane == 0) atomicAdd(loss, d * (1.25f / 16777216.f));
    }
    __syncthreads();

    // ---- gather + write z_q: 2 passes of 64 rows through smG (full 128B lines) ----
#pragma unroll 1
    for (int pass = 0; pass < 2; ++pass) {
        const int rbase = pass << 6;
#pragma unroll
        for (int i = 0; i < 8; ++i) {
            const int row = wave * 8 + i;                             // 0..63
            const unsigned code = sidx[rbase + row];
            const int src_chunk = (lane & 56) | ((lane & 7) ^ (row & 7));
            gload16(emb + (size_t)code * CDIM + src_chunk * 4,
                    (char*)smem + row * 1024 + lane * 16);
        }
        __syncthreads();
        {
            const int s = tid & 63, cg = tid >> 6;                    // 64 pos x 8 ch-groups
            float* ob = out + ((size_t)(b * 256 + cg * 32)) * 1024 + s0 + rbase + s;
#pragma unroll
            for (int c4 = 0; c4 < 8; ++c4) {
                const int lc4 = cg * 8 + c4;                          // logical 16B chunk
                const int p16 = (lc4 & 56) | ((lc4 & 7) ^ (s & 7));   // swizzled position
                float4 v = *(const float4*)((const char*)smem + s * 1024 + p16 * 16);
                ob[(size_t)(c4 * 4 + 0) * 1024] = v.x;
                ob[(size_t)(c4 * 4 + 1) * 1024] = v.y;
                ob[(size_t)(c4 * 4 + 2) * 1024] = v.z;
                ob[(size_t)(c4 * 4 + 3) * 1024] = v.w;
            }
        }
        if (pass == 0) __syncthreads();
    }
}

extern "C" void kernel_launch(void* const* d_in, const int* in_sizes, int n_in,
                              void* d_out, int out_size, void* d_ws, size_t ws_size,
                              hipStream_t stream)
{
    const float* z   = (const float*)d_in[0];
    const float* emb = (const float*)d_in[1];
    float* out = (float*)d_out;

    unsigned char* emb8 = (unsigned char*)d_ws;           // 256 KB
    float* e_sqs = (float*)((char*)d_ws + 262144);        // 4 KB
    float* loss  = out + 16777216;

    emb_prep<<<KCODES, 64, 0, stream>>>(emb, emb8, e_sqs, loss);
    vq_fused<<<512, 512, 0, stream>>>(z, emb, emb8, e_sqs, out, loss);
}